// Round 7
// baseline (194.915 us; speedup 1.0000x reference)
//
#include <hip/hip_runtime.h>

typedef __bf16 bf16x8 __attribute__((ext_vector_type(8)));
typedef float f32x4 __attribute__((ext_vector_type(4)));
typedef float fl4 __attribute__((ext_vector_type(4)));
typedef unsigned short us4 __attribute__((ext_vector_type(4)));
typedef unsigned short us8 __attribute__((ext_vector_type(8)));

__device__ __forceinline__ unsigned short f2bf(float f) {
  unsigned u = __builtin_bit_cast(unsigned, f);
  u += 0x7fffu + ((u >> 16) & 1u);
  return (unsigned short)(u >> 16);
}
__device__ __forceinline__ float bf2f(unsigned short h) {
  unsigned u = ((unsigned)h) << 16;
  return __builtin_bit_cast(float, u);
}

__device__ __forceinline__ void async16(const void* g, void* l) {
  __builtin_amdgcn_global_load_lds(
      (const __attribute__((address_space(1))) unsigned int*)g,
      (__attribute__((address_space(3))) unsigned int*)l, 16, 0, 0);
}

// ---------------- fp32 -> bf16 convert (x and W merged) ----------------
__global__ __launch_bounds__(256) void cvt_bf16_2(const float* __restrict__ sA,
                                                  unsigned short* __restrict__ dA, int nA,
                                                  const float* __restrict__ sB,
                                                  unsigned short* __restrict__ dB, int nB) {
  int i = blockIdx.x * 256 + threadIdx.x;
  const float* s;
  unsigned short* d;
  if (i < nA) {
    s = sA; d = dA;
  } else {
    i -= nA;
    if (i >= nB) return;
    s = sB; d = dB;
  }
  fl4 f = ((const fl4*)s)[i];
  us4 o;
  o[0] = f2bf(f[0]); o[1] = f2bf(f[1]); o[2] = f2bf(f[2]); o[3] = f2bf(f[3]);
  ((us4*)d)[i] = o;
}

// ---------------- transpose v: vT[b][c][t] = kqv[b*2048+t][2048+c] ----------------
__global__ __launch_bounds__(256) void transpose_v(const unsigned short* __restrict__ kqv,
                                                   unsigned short* __restrict__ vT) {
  int b = blockIdx.z;
  int t0 = blockIdx.x * 64;
  int c0 = blockIdx.y * 64;
  __shared__ unsigned short tile[64][68];
  int tid = threadIdx.x;
#pragma unroll
  for (int i = 0; i < 4; ++i) {
    int idx = i * 256 + tid;
    int r = idx >> 4;
    int c4 = (idx & 15) * 4;
    const unsigned short* src = kqv + ((size_t)(b * 2048 + t0 + r)) * 3072 + 2048 + c0 + c4;
    us4 v = *(const us4*)src;
    *(us4*)&tile[r][c4] = v;
  }
  __syncthreads();
#pragma unroll
  for (int i = 0; i < 4; ++i) {
    int idx = i * 256 + tid;
    int rc = idx >> 4;
    int t4 = (idx & 15) * 4;
    us4 v;
    v[0] = tile[t4 + 0][rc]; v[1] = tile[t4 + 1][rc];
    v[2] = tile[t4 + 2][rc]; v[3] = tile[t4 + 3][rc];
    unsigned short* dst = vT + ((size_t)(b * 1024 + c0 + rc)) * 2048 + t0 + t4;
    *(us4*)dst = v;
  }
}

// ---------------- 128xBN BK=32 bf16 MFMA GEMM, 4 waves, 2 blocks/CU -----------
// Round-1-proven engine, asymmetric tile. Wave layout 2M x 2N: wave 64 x BN/2.
// Single LDS buffer, 2 barriers/K-step; overlap comes from 2 independent
// blocks/CU drifting out of phase (m97/m114 mechanism), not intra-block sched.
// EPI 0: bf16 out + bias (kqv). EPI 1: bf16 out * scale, skip blocks fully
// above the causal diagonal. EPI 2: f32 out, K truncated at diagonal,
// heavy rows dispatched first.
template <int EPI, int BN>
__global__ __launch_bounds__(256, 2) void gemm_tile(
    const unsigned short* __restrict__ A, int lda, long long sA,
    const unsigned short* __restrict__ B, int ldb, long long sB,
    void* __restrict__ Cv, int ldc, long long sC,
    const float* __restrict__ bias, float scale, int K, int NBX) {
  int bx, by;
  const int bz = blockIdx.z;
  if (EPI == 0) {
    int flat = blockIdx.x;
    int q = (int)gridDim.x >> 3;            // grid % 8 == 0
    int swz = (flat & 7) * q + (flat >> 3); // XCD-contiguous remap
    bx = swz % NBX; by = swz / NBX;
  } else {
    bx = blockIdx.x; by = blockIdx.y;
    if (EPI == 2) by = (int)gridDim.y - 1 - by;      // heavy (large-K) first
    if (EPI == 1 && bx * BN > by * 128 + 127) return; // fully-masked block
  }
  A += (size_t)bz * sA;
  B += (size_t)bz * sB;
  const int rowBase = by * 128;
  const int colBase = bx * BN;
  const int nk = (EPI == 2) ? (rowBase + 128) / 32 : K / 32;

  constexpr int NB = BN / 32;       // acc columns (16-wide frags per wave half)
  constexpr int BOPS = BN / 64;     // B staging ops per thread
  __shared__ __align__(16) unsigned char lds[8192 + BN * 64];  // A 8KB | B BN*64B
  const int tid = threadIdx.x;
  const int lane = tid & 63;
  const int wid = tid >> 6;
  const int wr = (wid >> 1) * 64;        // M half
  const int wc = (wid & 1) * (BN / 2);   // N half
  const int l15 = lane & 15, l4 = lane >> 4;

  f32x4 acc[4][NB] = {};

  for (int kt = 0; kt < nk; ++kt) {
    __syncthreads();
    const int kof = kt * 32;
#pragma unroll
    for (int i = 0; i < 2; ++i) {
      int off = (i * 256 + tid) * 16;
      int r = off >> 6;
      int gblk = ((off >> 4) & 3) ^ ((r >> 1) & 3);
      async16(A + (size_t)(rowBase + r) * lda + kof + gblk * 8, lds + off);
    }
#pragma unroll
    for (int i = 0; i < BOPS; ++i) {
      int off = (i * 256 + tid) * 16;
      int r = off >> 6;
      int gblk = ((off >> 4) & 3) ^ ((r >> 1) & 3);
      async16(B + (size_t)(colBase + r) * ldb + kof + gblk * 8, lds + 8192 + off);
    }
    __syncthreads();

    bf16x8 af[4], bfr[NB];
#pragma unroll
    for (int m = 0; m < 4; ++m) {
      int row = wr + m * 16 + l15;
      int addr = row * 64 + (((l4 ^ (row >> 1)) & 3) * 16);
      af[m] = *(const bf16x8*)(lds + addr);
    }
#pragma unroll
    for (int n = 0; n < NB; ++n) {
      int row = wc + n * 16 + l15;
      int addr = row * 64 + (((l4 ^ (row >> 1)) & 3) * 16);
      bfr[n] = *(const bf16x8*)(lds + 8192 + addr);
    }
#pragma unroll
    for (int m = 0; m < 4; ++m)
#pragma unroll
      for (int n = 0; n < NB; ++n)
        acc[m][n] = __builtin_amdgcn_mfma_f32_16x16x32_bf16(af[m], bfr[n], acc[m][n], 0, 0, 0);
  }

  const int cr = l4 * 4;
  if constexpr (EPI == 0) {
    unsigned short* C = (unsigned short*)Cv;
#pragma unroll
    for (int n = 0; n < NB; ++n) {
      int col = colBase + wc + n * 16 + l15;
      float bv = bias[col];
#pragma unroll
      for (int m = 0; m < 4; ++m) {
        int row = rowBase + wr + m * 16 + cr;
#pragma unroll
        for (int i = 0; i < 4; ++i)
          C[(size_t)(row + i) * ldc + col] = f2bf(acc[m][n][i] + bv);
      }
    }
  } else if constexpr (EPI == 1) {
    unsigned short* C = (unsigned short*)Cv + (size_t)bz * sC;
#pragma unroll
    for (int n = 0; n < NB; ++n) {
      int col = colBase + wc + n * 16 + l15;
#pragma unroll
      for (int m = 0; m < 4; ++m) {
        int row = rowBase + wr + m * 16 + cr;
#pragma unroll
        for (int i = 0; i < 4; ++i)
          C[(size_t)(row + i) * ldc + col] = f2bf(acc[m][n][i] * scale);
      }
    }
  } else {
    float* C = (float*)Cv + (size_t)bz * sC;
#pragma unroll
    for (int n = 0; n < NB; ++n) {
      int col = colBase + wc + n * 16 + l15;
#pragma unroll
      for (int m = 0; m < 4; ++m) {
        int row = rowBase + wr + m * 16 + cr;
#pragma unroll
        for (int i = 0; i < 4; ++i)
          C[(size_t)(row + i) * ldc + col] = acc[m][n][i];
      }
    }
  }
}

// ---------------- causal softmax over S rows (in place, bf16) ----------------
// Loads only cols < nv; stores cols < bound = ceil128(t+1) — exactly the
// K-range gemm_tile<2,128>'s truncation reads (zero-fills masked remainder,
// including diagonal-block cols g1 never computed).
__global__ __launch_bounds__(256) void softmax_causal(unsigned short* __restrict__ S) {
  const int T = 2048;
  int t = blockIdx.x, b = blockIdx.y;
  unsigned short* row = S + ((size_t)b * T + t) * T;
  const int nv = t + 1;
  const int bound = ((t >> 7) + 1) << 7;
  int tid = threadIdx.x;
  int lane = tid & 63, wid = tid >> 6;
  int s0 = tid * 8;
  us8 raw = {};
  if (s0 < nv) raw = *(const us8*)(row + s0);
  float v[8];
  float m = -3.0e38f;
#pragma unroll
  for (int j = 0; j < 8; ++j) {
    v[j] = bf2f(raw[j]);
    if (s0 + j < nv) m = fmaxf(m, v[j]);
  }
#pragma unroll
  for (int o = 32; o > 0; o >>= 1) m = fmaxf(m, __shfl_xor(m, o, 64));
  __shared__ float red[4];
  if (lane == 0) red[wid] = m;
  __syncthreads();
  m = fmaxf(fmaxf(red[0], red[1]), fmaxf(red[2], red[3]));
  __syncthreads();
  float sum = 0.f;
#pragma unroll
  for (int j = 0; j < 8; ++j) {
    float e = (s0 + j < nv) ? exp2f(v[j] - m) : 0.f;
    v[j] = e;
    sum += e;
  }
#pragma unroll
  for (int o = 32; o > 0; o >>= 1) sum += __shfl_xor(sum, o, 64);
  if (lane == 0) red[wid] = sum;
  __syncthreads();
  sum = red[0] + red[1] + red[2] + red[3];
  float inv = 1.0f / sum;
  if (s0 < bound) {
    us8 outv;
#pragma unroll
    for (int j = 0; j < 8; ++j) outv[j] = f2bf(v[j] * inv);
    *(us8*)(row + s0) = outv;
  }
}

extern "C" void kernel_launch(void* const* d_in, const int* in_sizes, int n_in,
                              void* d_out, int out_size, void* d_ws, size_t ws_size,
                              hipStream_t stream) {
  const float* x = (const float*)d_in[0];      // [4,2048,1024]
  const float* W = (const float*)d_in[1];      // [3072,1024]
  const float* bias = (const float*)d_in[2];   // [3072]
  float* out = (float*)d_out;                  // [4,2048,1024]

  char* ws = (char*)d_ws;
  // layout: xbf 16MB (aliased by vT after gemm0) | wbf 6MB | kqv 48MB | S 32MB
  if (ws_size < 106954752u) return;
  unsigned short* xbf = (unsigned short*)(ws);
  unsigned short* vT = xbf;  // alias: xbf dead after gemm_tile<0>
  unsigned short* wbf = (unsigned short*)(ws + 16777216);
  unsigned short* kqv = (unsigned short*)(ws + 23068672);
  unsigned short* S = (unsigned short*)(ws + 73400320);

  const float kSoftmaxScale = 1.4426950408889634f / 32.0f;  // log2(e)/sqrt(1024)

  cvt_bf16_2<<<11264, 256, 0, stream>>>(x, xbf, 2097152, W, wbf, 786432);

  // kqv = x @ W^T + b (M=8192, N=3072, K=1024): 64x12 = 768 blocks = 3 rounds
  gemm_tile<0, 256><<<dim3(768, 1, 1), 256, 0, stream>>>(
      xbf, 1024, 0LL, wbf, 1024, 0LL, kqv, 3072, 0LL, bias, 1.0f, 1024, 12);

  transpose_v<<<dim3(32, 16, 4), 256, 0, stream>>>(kqv, vT);

  // S = (k @ q^T) * log2e/32 (bf16), 128x256 tiles, 288 live blocks
  gemm_tile<1, 256><<<dim3(8, 16, 4), 256, 0, stream>>>(
      kqv, 3072, 2048LL * 3072, kqv + 1024, 3072, 2048LL * 3072,
      S, 2048, 2048LL * 2048, nullptr, kSoftmaxScale, 1024, 0);

  softmax_causal<<<dim3(2048, 4), 256, 0, stream>>>(S);

  // out = P @ vT^T (fp32), 128x128 tiles, K truncated at diagonal, heavy-first
  gemm_tile<2, 128><<<dim3(8, 16, 4), 256, 0, stream>>>(
      S, 2048, 2048LL * 2048, vT, 2048, 1024LL * 2048,
      out, 1024, 2048LL * 1024, nullptr, 1.0f, 2048, 0);
}